// Round 1
// baseline (303.577 us; speedup 1.0000x reference)
//
#include <hip/hip_runtime.h>
#include <hip/hip_bf16.h>
#include <stdint.h>

typedef __attribute__((ext_vector_type(8))) short short8;
typedef __attribute__((ext_vector_type(4))) float floatx4;

// ---------------- db4 filter constants ----------------
__device__ __constant__ float c_DL[8] = {
    -0.010597401784997278f, 0.032883011666982945f, 0.030841381835986965f,
    -0.18703481171888114f, -0.02798376941698385f, 0.6308807679295904f,
    0.7148465705525415f, 0.23037781330885523f};
__device__ __constant__ float c_DH[8] = {
    -0.23037781330885523f, 0.7148465705525415f, -0.6308807679295904f,
    -0.02798376941698385f, 0.18703481171888114f, 0.030841381835986965f,
    -0.032883011666982945f, -0.010597401784997278f};
// REC_LO = reverse(DEC_LO) (also used as reversed-order analysis lowpass)
__device__ __constant__ float c_RL[8] = {
    0.23037781330885523f, 0.7148465705525415f, 0.6308807679295904f,
    -0.02798376941698385f, -0.18703481171888114f, 0.030841381835986965f,
    0.032883011666982945f, -0.010597401784997278f};
__device__ __constant__ float c_RH[8] = {
    -0.010597401784997278f, -0.032883011666982945f, 0.030841381835986965f,
    0.18703481171888114f, -0.02798376941698385f, -0.6308807679295904f,
    0.7148465705525415f, -0.23037781330885523f};

__device__ __forceinline__ float bflo(uint32_t u) { return __uint_as_float(u << 16); }
__device__ __forceinline__ float bfhi(uint32_t u) { return __uint_as_float(u & 0xffff0000u); }
__device__ __forceinline__ float ldf(const float* p, size_t i) { return p[i]; }
__device__ __forceinline__ float ldf(const __hip_bfloat16* p, size_t i) { return __bfloat162float(p[i]); }
__device__ __forceinline__ void stf(float* p, size_t i, float v) { p[i] = v; }
__device__ __forceinline__ void stf(__hip_bfloat16* p, size_t i, float v) { p[i] = __float2bfloat16(v); }
__device__ __forceinline__ short f2bs(float f) {
  __hip_bfloat16 h = __float2bfloat16(f);
  return *reinterpret_cast<short*>(&h);
}

__device__ __forceinline__ int reflect_idx(int t, int n) {
  if (t < 0) t = -1 - t;
  if (t >= n) t = 2 * n - 1 - t;
  return t;
}

// Row strides (padded for aligned vector access)
#define S1R 4100
#define S2R 2056

// ---------------- Level-1 DWT: x (B,N,C) fp32, transposed read -> a1,d1 (B*C, stride 4100) bf16
#define NT1 134
__global__ __launch_bounds__(256) void k_dwt_first(const float* __restrict__ x,
                                                   __hip_bfloat16* __restrict__ outa,
                                                   __hip_bfloat16* __restrict__ outd) {
  const int b = blockIdx.y;
  const int k0 = blockIdx.x * 64;
  const int tid = threadIdx.x;
  __shared__ float xs[NT1 * 65];

  const float4* x4 = (const float4*)x;
  for (int idx = tid; idx < NT1 * 16; idx += 256) {
    int nl = idx >> 4, cq = idx & 15;
    int t = 2 * k0 - 6 + nl;
    int n = reflect_idx(t, 8192);
    float4 v = x4[((size_t)b * 8192 + n) * 16 + cq];
    float* d = &xs[nl * 65 + 4 * cq];
    d[0] = v.x; d[1] = v.y; d[2] = v.z; d[3] = v.w;
  }
  __syncthreads();

  const int kk = tid & 63;
  const int k = k0 + kk;
  if (k >= 4099) return;
  for (int c = (tid >> 6); c < 64; c += 4) {
    float lo = 0.f, hi = 0.f;
#pragma unroll
    for (int j = 0; j < 8; ++j) {
      float v = xs[(2 * kk + 7 - j) * 65 + c];
      lo += c_DL[j] * v;
      hi += c_DH[j] * v;
    }
    size_t s = (size_t)b * 64 + c;
    outa[s * S1R + k] = __float2bfloat16(lo);
    outd[s * S1R + k] = __float2bfloat16(hi);
  }
}

// ---------------- Fused analysis levels 2..4, one row per block
__global__ __launch_bounds__(256) void k_ana234(const __hip_bfloat16* __restrict__ a1,
                                                __hip_bfloat16* __restrict__ d2o,
                                                float* __restrict__ d3o,
                                                float* __restrict__ a4o,
                                                float* __restrict__ d4o) {
  const int r = blockIdx.x;
  const int tid = threadIdx.x;
  __shared__ float s1[4100];
  __shared__ float s2[2054];
  __shared__ float s3[1032];

  const uint2* row2 = (const uint2*)(a1 + (size_t)r * S1R);
  for (int i = tid; i < 1025; i += 256) {
    uint2 u = row2[i];
    int e = 4 * i;
    s1[e] = bflo(u.x); s1[e + 1] = bfhi(u.x);
    s1[e + 2] = bflo(u.y); s1[e + 3] = bfhi(u.y);
  }
  __syncthreads();

  // level 2: n=4099 -> m=2053
  for (int k = tid; k < 2053; k += 256) {
    float lo = 0.f, hi = 0.f;
    if (k >= 3 && k <= 2048) {
      const float2* p = (const float2*)&s1[2 * k - 6];
      float2 v0 = p[0], v1 = p[1], v2 = p[2], v3 = p[3];
      lo = c_RL[0]*v0.x + c_RL[1]*v0.y + c_RL[2]*v1.x + c_RL[3]*v1.y +
           c_RL[4]*v2.x + c_RL[5]*v2.y + c_RL[6]*v3.x + c_RL[7]*v3.y;
      hi = c_RH[0]*v0.x + c_RH[1]*v0.y + c_RH[2]*v1.x + c_RH[3]*v1.y +
           c_RH[4]*v2.x + c_RH[5]*v2.y + c_RH[6]*v3.x + c_RH[7]*v3.y;
    } else {
#pragma unroll
      for (int j = 0; j < 8; ++j) {
        float v = s1[reflect_idx(2 * k + 1 - j, 4099)];
        lo += c_DL[j] * v; hi += c_DH[j] * v;
      }
    }
    d2o[(size_t)r * S2R + k] = __float2bfloat16(hi);
    s2[k] = lo;
  }
  __syncthreads();

  // level 3: n=2053 -> m=1030
  for (int k = tid; k < 1030; k += 256) {
    float lo = 0.f, hi = 0.f;
    if (k >= 3 && k <= 1025) {
      const float2* p = (const float2*)&s2[2 * k - 6];
      float2 v0 = p[0], v1 = p[1], v2 = p[2], v3 = p[3];
      lo = c_RL[0]*v0.x + c_RL[1]*v0.y + c_RL[2]*v1.x + c_RL[3]*v1.y +
           c_RL[4]*v2.x + c_RL[5]*v2.y + c_RL[6]*v3.x + c_RL[7]*v3.y;
      hi = c_RH[0]*v0.x + c_RH[1]*v0.y + c_RH[2]*v1.x + c_RH[3]*v1.y +
           c_RH[4]*v2.x + c_RH[5]*v2.y + c_RH[6]*v3.x + c_RH[7]*v3.y;
    } else {
#pragma unroll
      for (int j = 0; j < 8; ++j) {
        float v = s2[reflect_idx(2 * k + 1 - j, 2053)];
        lo += c_DL[j] * v; hi += c_DH[j] * v;
      }
    }
    d3o[(size_t)r * 1030 + k] = hi;
    s3[k] = lo;
  }
  __syncthreads();

  // level 4: n=1030 -> m=518
  for (int k = tid; k < 518; k += 256) {
    float lo = 0.f, hi = 0.f;
    if (k >= 3 && k <= 514) {
      const float2* p = (const float2*)&s3[2 * k - 6];
      float2 v0 = p[0], v1 = p[1], v2 = p[2], v3 = p[3];
      lo = c_RL[0]*v0.x + c_RL[1]*v0.y + c_RL[2]*v1.x + c_RL[3]*v1.y +
           c_RL[4]*v2.x + c_RL[5]*v2.y + c_RL[6]*v3.x + c_RL[7]*v3.y;
      hi = c_RH[0]*v0.x + c_RH[1]*v0.y + c_RH[2]*v1.x + c_RH[3]*v1.y +
           c_RH[4]*v2.x + c_RH[5]*v2.y + c_RH[6]*v3.x + c_RH[7]*v3.y;
    } else {
#pragma unroll
      for (int j = 0; j < 8; ++j) {
        float v = s3[reflect_idx(2 * k + 1 - j, 1030)];
        lo += c_DL[j] * v; hi += c_DH[j] * v;
      }
    }
    a4o[(size_t)r * 518 + k] = lo;
    d4o[(size_t)r * 518 + k] = hi;
  }
}

// ---------------- Channel mixing v4: one block per coefficient position p.
// Every weight element and every activation element is fetched from HBM exactly
// once across the whole grid. 518 blocks, 48 KB LDS each.
// XCD-contiguous p mapping: all blocks on one XCD own a contiguous p-range so
// their (column-gather) line requests overlap in that XCD's L2.
__global__ __launch_bounds__(256) void k_mix_p(const float* __restrict__ a4,
                                               const float* __restrict__ d4,
                                               const float* __restrict__ w1,
                                               const float* __restrict__ w2,
                                               float* __restrict__ am,
                                               float* __restrict__ dm) {
  // bijective bx -> p with xcd = bx%8 owning contiguous p range (518 = 6*65 + 2*64)
  const int bx = blockIdx.x;
  const int xcd = bx & 7;
  const int j = bx >> 3;
  const int p = (xcd < 6) ? (xcd * 65 + j) : (390 + (xcd - 6) * 64 + j);

  __shared__ float w1s[4096];  // w1s[i*64+o]
  __shared__ float w2s[4096];
  __shared__ float as[2048];   // as[i*32+b]  (transposed for conflict-free reads)
  __shared__ float ds[2048];

  const int tid = threadIdx.x;
  for (int idx = tid; idx < 4096; idx += 256) {
    w1s[idx] = w1[(size_t)idx * 518 + p];
    w2s[idx] = w2[(size_t)idx * 518 + p];
  }
  for (int idx = tid; idx < 2048; idx += 256) {
    int i = idx >> 5, b = idx & 31;
    as[idx] = a4[(size_t)(b * 64 + i) * 518 + p];
    ds[idx] = d4[(size_t)(b * 64 + i) * 518 + p];
  }
  __syncthreads();

  // register tile: 2 batches x 4 outputs per thread, for both a and d mixes
  const int o0 = (tid & 15) * 4;
  const int bq = tid >> 4;  // 0..15 ; batches {bq, bq+16}
  floatx4 acc0 = {0.f, 0.f, 0.f, 0.f}, acc1 = {0.f, 0.f, 0.f, 0.f};
  floatx4 accd0 = {0.f, 0.f, 0.f, 0.f}, accd1 = {0.f, 0.f, 0.f, 0.f};

#pragma unroll 4
  for (int i = 0; i < 64; ++i) {
    floatx4 wv1 = *(const floatx4*)&w1s[i * 64 + o0];
    floatx4 wv2 = *(const floatx4*)&w2s[i * 64 + o0];
    float a0 = as[i * 32 + bq];
    float a1 = as[i * 32 + bq + 16];
    float dv0 = ds[i * 32 + bq];
    float dv1 = ds[i * 32 + bq + 16];
#pragma unroll
    for (int q = 0; q < 4; ++q) {
      acc0[q] += a0 * wv1[q];
      acc1[q] += a1 * wv1[q];
      accd0[q] += dv0 * wv2[q];
      accd1[q] += dv1 * wv2[q];
    }
  }

#pragma unroll
  for (int q = 0; q < 4; ++q) {
    size_t s0 = (size_t)(bq * 64 + o0 + q) * 518 + p;
    size_t s1 = (size_t)((bq + 16) * 64 + o0 + q) * 518 + p;
    am[s0] = acc0[q];
    am[s1] = acc1[q];
    dm[s0] = accd0[q];
    dm[s1] = accd1[q];
  }
}

// ---------------- Fused synthesis: idwt level4->r3, then level3 -> recon2 (bf16)
__global__ __launch_bounds__(256) void k_syn32(const float* __restrict__ a4m,
                                               const float* __restrict__ d4m,
                                               const float* __restrict__ d3,
                                               __hip_bfloat16* __restrict__ r2out) {
  const int r = blockIdx.x;
  const int tid = threadIdx.x;
  __shared__ float sa[518], sd[518], s3d[1030], r3[1030];
  for (int i = tid; i < 518; i += 256) {
    sa[i] = a4m[(size_t)r * 518 + i];
    sd[i] = d4m[(size_t)r * 518 + i];
  }
  for (int i = tid; i < 1030; i += 256) s3d[i] = d3[(size_t)r * 1030 + i];
  __syncthreads();
  for (int s = tid; s < 1030; s += 256) {
    int u = s >> 1, par = s & 1;
    float acc = 0.f;
#pragma unroll
    for (int t = 0; t < 4; ++t) {
      int i = u + 3 - t;
      float fl = par ? c_RL[2 * t + 1] : c_RL[2 * t];
      float fh = par ? c_RH[2 * t + 1] : c_RH[2 * t];
      acc += fl * sa[i] + fh * sd[i];
    }
    r3[s] = acc;
  }
  __syncthreads();
  for (int s = tid; s < 2053; s += 256) {
    int u = s >> 1, par = s & 1;
    float acc = 0.f;
#pragma unroll
    for (int t = 0; t < 4; ++t) {
      int i = u + 3 - t;
      float fl = par ? c_RL[2 * t + 1] : c_RL[2 * t];
      float fh = par ? c_RH[2 * t + 1] : c_RH[2 * t];
      acc += fl * r3[i] + fh * s3d[i];
    }
    r2out[(size_t)r * S2R + s] = __float2bfloat16(acc);
  }
}

// ---------------- Generic IDWT level with strides (used for level 2 -> recon1)
template <typename TCa, typename TCd, typename TOut>
__global__ void k_idwt(const TCa* __restrict__ ca, const TCd* __restrict__ cd,
                       TOut* __restrict__ out, int m, int out_len, int sin, int sout) {
  int s = blockIdx.x * blockDim.x + threadIdx.x;
  if (s >= out_len) return;
  const TCa* pa = ca + (size_t)blockIdx.y * sin;
  const TCd* pd = cd + (size_t)blockIdx.y * sin;
  int u = s >> 1, par = s & 1;
  float acc = 0.f;
#pragma unroll
  for (int t = 0; t < 4; ++t) {
    int i = u + 3 - t;
    float fl = par ? c_RL[2 * t + 1] : c_RL[2 * t];
    float fh = par ? c_RH[2 * t + 1] : c_RH[2 * t];
    acc += fl * ldf(pa, i) + fh * ldf(pd, i);
  }
  stf(out, (size_t)blockIdx.y * sout + s, acc);
}

// ---------------- Epilogue: MFMA dense shortcut + final IDWT + bias + mish -> fp32
// block 256 (4 waves), tile 64n x 64o, grid (128, 32)
__global__ __launch_bounds__(256) void k_epilogue(const __hip_bfloat16* __restrict__ r1,
                                                  const __hip_bfloat16* __restrict__ dd1,
                                                  const float* __restrict__ x,
                                                  const float* __restrict__ dk,
                                                  const float* __restrict__ bias,
                                                  float* __restrict__ out) {
  const int b = blockIdx.y;
  const int n0 = blockIdx.x * 64;
  const int u0 = n0 >> 1;
  const int tid = threadIdx.x;
  const int lane = tid & 63;
  const int w = tid >> 6;

  __shared__ __hip_bfloat16 Kt[64 * 72];  // Kt[o][c], row pad to 72 (144B, 16B-aligned rows)
  __shared__ float ra[35 * 65];
  __shared__ float rd[35 * 65];

  // stage Kt = K^T (bf16)
  {
    const float4* dk4 = (const float4*)dk;
    for (int idx = tid; idx < 1024; idx += 256) {
      int c = idx >> 4, o0 = (idx & 15) * 4;
      float4 v = dk4[idx];  // dk[c][o0..o0+3]
      Kt[(o0 + 0) * 72 + c] = __float2bfloat16(v.x);
      Kt[(o0 + 1) * 72 + c] = __float2bfloat16(v.y);
      Kt[(o0 + 2) * 72 + c] = __float2bfloat16(v.z);
      Kt[(o0 + 3) * 72 + c] = __float2bfloat16(v.w);
    }
  }
  // stage ra/rd (35 coeffs x 64 channels)
  {
    int o2 = tid >> 2;
    const __hip_bfloat16* pr = r1 + (size_t)(b * 64 + o2) * S1R + u0;
    const __hip_bfloat16* pd = dd1 + (size_t)(b * 64 + o2) * S1R + u0;
    for (int il = (tid & 3); il < 35; il += 4) {
      ra[il * 65 + o2] = __bfloat162float(pr[il]);
      rd[il * 65 + o2] = __bfloat162float(pd[il]);
    }
  }
  __syncthreads();

  const int m16 = lane & 15;        // A-row within 16-tile / B-col within o-tile
  const int kq = (lane >> 4) * 8;   // k sub-offset
  const int nrow = w * 16 + m16;    // this lane's A row (n_loc) for loading
  const float* xrow = x + ((size_t)b * 8192 + n0 + nrow) * 64;

  floatx4 acc[4];
#pragma unroll
  for (int ot = 0; ot < 4; ++ot) acc[ot] = (floatx4){0.f, 0.f, 0.f, 0.f};

#pragma unroll
  for (int ks = 0; ks < 2; ++ks) {
    float4 xa = *(const float4*)(xrow + ks * 32 + kq);
    float4 xb = *(const float4*)(xrow + ks * 32 + kq + 4);
    short8 af;
    af[0] = f2bs(xa.x); af[1] = f2bs(xa.y); af[2] = f2bs(xa.z); af[3] = f2bs(xa.w);
    af[4] = f2bs(xb.x); af[5] = f2bs(xb.y); af[6] = f2bs(xb.z); af[7] = f2bs(xb.w);
#pragma unroll
    for (int ot = 0; ot < 4; ++ot) {
      short8 bf = *(const short8*)&Kt[(ot * 16 + m16) * 72 + ks * 32 + kq];
      acc[ot] = __builtin_amdgcn_mfma_f32_16x16x32_bf16(af, bf, acc[ot], 0, 0, 0);
    }
  }

  // epilogue: C/D layout col=lane&15 (o), row=(lane>>4)*4+reg (n)
  const int rbase = (lane >> 4) * 4;
#pragma unroll
  for (int ot = 0; ot < 4; ++ot) {
    int o_loc = ot * 16 + m16;
    float bo = bias[o_loc];
#pragma unroll
    for (int rg = 0; rg < 4; ++rg) {
      int n_loc = w * 16 + rbase + rg;
      int ul = n_loc >> 1, par = n_loc & 1;
      float wv = 0.f;
#pragma unroll
      for (int t = 0; t < 4; ++t) {
        int i = ul + 3 - t;
        float fl = par ? c_RL[2 * t + 1] : c_RL[2 * t];
        float fh = par ? c_RH[2 * t + 1] : c_RH[2 * t];
        wv += fl * ra[i * 65 + o_loc] + fh * rd[i * 65 + o_loc];
      }
      float v = acc[ot][rg] + wv + bo;
      float e = __expf(fminf(v, 15.f));
      float num = e * (e + 2.f);
      float mm = (v > 15.f) ? v : v * (num / (num + 2.f));
      out[((size_t)b * 8192 + n0 + n_loc) * 64 + o_loc] = mm;
    }
  }
}

// ---------------- host ----------------
extern "C" void kernel_launch(void* const* d_in, const int* in_sizes, int n_in,
                              void* d_out, int out_size, void* d_ws, size_t ws_size,
                              hipStream_t stream) {
  const float* x    = (const float*)d_in[0];
  const float* w1   = (const float*)d_in[1];
  const float* w2   = (const float*)d_in[2];
  const float* dk   = (const float*)d_in[3];
  const float* bias = (const float*)d_in[4];
  float* out = (float*)d_out;

  const size_t R = 2048;

  float* wf = (float*)d_ws;
  float* d3f = wf; wf += R * 1030;
  float* a4f = wf; wf += R * 518;
  float* d4f = wf; wf += R * 518;
  float* a4m = wf; wf += R * 518;
  float* d4m = wf; wf += R * 518;
  __hip_bfloat16* wb = (__hip_bfloat16*)wf;
  __hip_bfloat16* a1b = wb; wb += R * S1R;  // analysis a1, later recon1
  __hip_bfloat16* d1b = wb; wb += R * S1R;
  __hip_bfloat16* a2b = wb; wb += R * S2R;  // analysis a2 unused; holds recon2
  __hip_bfloat16* d2b = wb; wb += R * S2R;
  // total ~75.8 MB

  k_dwt_first<<<dim3(65, 32), 256, 0, stream>>>(x, a1b, d1b);
  k_ana234<<<dim3(2048), 256, 0, stream>>>(a1b, d2b, d3f, a4f, d4f);
  // one block per p; weights read exactly once from HBM
  k_mix_p<<<dim3(518), 256, 0, stream>>>(a4f, d4f, w1, w2, a4m, d4m);
  k_syn32<<<dim3(2048), 256, 0, stream>>>(a4m, d4m, d3f, a2b);
  k_idwt<__hip_bfloat16, __hip_bfloat16, __hip_bfloat16>
      <<<dim3((4099 + 255) / 256, 2048), 256, 0, stream>>>(a2b, d2b, a1b, 2053, 4099, S2R, S1R);
  k_epilogue<<<dim3(128, 32), 256, 0, stream>>>(a1b, d1b, x, dk, bias, out);
}

// Round 2
// 285.116 us; speedup vs baseline: 1.0648x; 1.0648x over previous
//
#include <hip/hip_runtime.h>
#include <hip/hip_bf16.h>
#include <stdint.h>

typedef __attribute__((ext_vector_type(8))) short short8;
typedef __attribute__((ext_vector_type(4))) float floatx4;

// ---------------- db4 filter constants ----------------
__device__ __constant__ float c_DL[8] = {
    -0.010597401784997278f, 0.032883011666982945f, 0.030841381835986965f,
    -0.18703481171888114f, -0.02798376941698385f, 0.6308807679295904f,
    0.7148465705525415f, 0.23037781330885523f};
__device__ __constant__ float c_DH[8] = {
    -0.23037781330885523f, 0.7148465705525415f, -0.6308807679295904f,
    -0.02798376941698385f, 0.18703481171888114f, 0.030841381835986965f,
    -0.032883011666982945f, -0.010597401784997278f};
// REC_LO = reverse(DEC_LO) (also used as reversed-order analysis lowpass)
__device__ __constant__ float c_RL[8] = {
    0.23037781330885523f, 0.7148465705525415f, 0.6308807679295904f,
    -0.02798376941698385f, -0.18703481171888114f, 0.030841381835986965f,
    0.032883011666982945f, -0.010597401784997278f};
__device__ __constant__ float c_RH[8] = {
    -0.010597401784997278f, -0.032883011666982945f, 0.030841381835986965f,
    0.18703481171888114f, -0.02798376941698385f, -0.6308807679295904f,
    0.7148465705525415f, -0.23037781330885523f};

__device__ __forceinline__ float bflo(uint32_t u) { return __uint_as_float(u << 16); }
__device__ __forceinline__ float bfhi(uint32_t u) { return __uint_as_float(u & 0xffff0000u); }
__device__ __forceinline__ float ldf(const float* p, size_t i) { return p[i]; }
__device__ __forceinline__ float ldf(const __hip_bfloat16* p, size_t i) { return __bfloat162float(p[i]); }
__device__ __forceinline__ void stf(float* p, size_t i, float v) { p[i] = v; }
__device__ __forceinline__ void stf(__hip_bfloat16* p, size_t i, float v) { p[i] = __float2bfloat16(v); }
__device__ __forceinline__ short f2bs(float f) {
  __hip_bfloat16 h = __float2bfloat16(f);
  return *reinterpret_cast<short*>(&h);
}

__device__ __forceinline__ int reflect_idx(int t, int n) {
  if (t < 0) t = -1 - t;
  if (t >= n) t = 2 * n - 1 - t;
  return t;
}

// Row strides (padded for aligned vector access)
#define S1R 4100
#define S2R 2056

// ---------------- Weight transpose: w[i][o][p] -> wt[p][i*64+o]
// Tiled LDS transpose, coalesced reads (256B row segments) and writes (256B rows).
__global__ __launch_bounds__(256) void k_wT(const float* __restrict__ w1,
                                            const float* __restrict__ w2,
                                            float* __restrict__ wt1,
                                            float* __restrict__ wt2) {
  const float* w = blockIdx.z ? w2 : w1;
  float* wt = blockIdx.z ? wt2 : wt1;
  const int io0 = blockIdx.x * 64;
  const int p0 = blockIdx.y * 64;
  const int pw = min(64, 518 - p0);
  const int tid = threadIdx.x;
  __shared__ float ts[64 * 65];
  for (int idx = tid; idx < 64 * 64; idx += 256) {
    int row = idx >> 6, col = idx & 63;
    if (col < pw) ts[row * 65 + col] = w[(size_t)(io0 + row) * 518 + p0 + col];
  }
  __syncthreads();
  for (int idx = tid; idx < 64 * 64; idx += 256) {
    int pl = idx >> 6, io = idx & 63;
    if (pl < pw) wt[(size_t)(p0 + pl) * 4096 + io0 + io] = ts[io * 65 + pl];
  }
}

// ---------------- Level-1 DWT: x (B,N,C) fp32, transposed read -> a1,d1 (B*C, stride 4100) bf16
#define NT1 134
__global__ __launch_bounds__(256) void k_dwt_first(const float* __restrict__ x,
                                                   __hip_bfloat16* __restrict__ outa,
                                                   __hip_bfloat16* __restrict__ outd) {
  const int b = blockIdx.y;
  const int k0 = blockIdx.x * 64;
  const int tid = threadIdx.x;
  __shared__ float xs[NT1 * 65];

  const float4* x4 = (const float4*)x;
  for (int idx = tid; idx < NT1 * 16; idx += 256) {
    int nl = idx >> 4, cq = idx & 15;
    int t = 2 * k0 - 6 + nl;
    int n = reflect_idx(t, 8192);
    float4 v = x4[((size_t)b * 8192 + n) * 16 + cq];
    float* d = &xs[nl * 65 + 4 * cq];
    d[0] = v.x; d[1] = v.y; d[2] = v.z; d[3] = v.w;
  }
  __syncthreads();

  const int kk = tid & 63;
  const int k = k0 + kk;
  if (k >= 4099) return;
  for (int c = (tid >> 6); c < 64; c += 4) {
    float lo = 0.f, hi = 0.f;
#pragma unroll
    for (int j = 0; j < 8; ++j) {
      float v = xs[(2 * kk + 7 - j) * 65 + c];
      lo += c_DL[j] * v;
      hi += c_DH[j] * v;
    }
    size_t s = (size_t)b * 64 + c;
    outa[s * S1R + k] = __float2bfloat16(lo);
    outd[s * S1R + k] = __float2bfloat16(hi);
  }
}

// ---------------- Fused analysis levels 2..4, one row per block
// Level-4 outputs are written TRANSPOSED: a4t[k*2048 + s], s = i*32 + b.
// Block->row mapping is XCD-contiguous in s so the 16 writers of each 64B line
// land on the same XCD's L2 and merge.
__global__ __launch_bounds__(256) void k_ana234(const __hip_bfloat16* __restrict__ a1,
                                                __hip_bfloat16* __restrict__ d2o,
                                                float* __restrict__ d3o,
                                                float* __restrict__ a4o,
                                                float* __restrict__ d4o) {
  const int bid = blockIdx.x;
  const int s = (bid & 7) * 256 + (bid >> 3);  // bijective, XCD-contiguous s-range
  const int i_ch = s >> 5;                     // input channel 0..63
  const int bb = s & 31;                       // batch 0..31
  const int r = bb * 64 + i_ch;                // row in a1/d2/d3 layouts
  const int tid = threadIdx.x;
  __shared__ float s1[4100];
  __shared__ float s2[2054];
  __shared__ float s3[1032];

  const uint2* row2 = (const uint2*)(a1 + (size_t)r * S1R);
  for (int i = tid; i < 1025; i += 256) {
    uint2 u = row2[i];
    int e = 4 * i;
    s1[e] = bflo(u.x); s1[e + 1] = bfhi(u.x);
    s1[e + 2] = bflo(u.y); s1[e + 3] = bfhi(u.y);
  }
  __syncthreads();

  // level 2: n=4099 -> m=2053
  for (int k = tid; k < 2053; k += 256) {
    float lo = 0.f, hi = 0.f;
    if (k >= 3 && k <= 2048) {
      const float2* p = (const float2*)&s1[2 * k - 6];
      float2 v0 = p[0], v1 = p[1], v2 = p[2], v3 = p[3];
      lo = c_RL[0]*v0.x + c_RL[1]*v0.y + c_RL[2]*v1.x + c_RL[3]*v1.y +
           c_RL[4]*v2.x + c_RL[5]*v2.y + c_RL[6]*v3.x + c_RL[7]*v3.y;
      hi = c_RH[0]*v0.x + c_RH[1]*v0.y + c_RH[2]*v1.x + c_RH[3]*v1.y +
           c_RH[4]*v2.x + c_RH[5]*v2.y + c_RH[6]*v3.x + c_RH[7]*v3.y;
    } else {
#pragma unroll
      for (int j = 0; j < 8; ++j) {
        float v = s1[reflect_idx(2 * k + 1 - j, 4099)];
        lo += c_DL[j] * v; hi += c_DH[j] * v;
      }
    }
    d2o[(size_t)r * S2R + k] = __float2bfloat16(hi);
    s2[k] = lo;
  }
  __syncthreads();

  // level 3: n=2053 -> m=1030
  for (int k = tid; k < 1030; k += 256) {
    float lo = 0.f, hi = 0.f;
    if (k >= 3 && k <= 1025) {
      const float2* p = (const float2*)&s2[2 * k - 6];
      float2 v0 = p[0], v1 = p[1], v2 = p[2], v3 = p[3];
      lo = c_RL[0]*v0.x + c_RL[1]*v0.y + c_RL[2]*v1.x + c_RL[3]*v1.y +
           c_RL[4]*v2.x + c_RL[5]*v2.y + c_RL[6]*v3.x + c_RL[7]*v3.y;
      hi = c_RH[0]*v0.x + c_RH[1]*v0.y + c_RH[2]*v1.x + c_RH[3]*v1.y +
           c_RH[4]*v2.x + c_RH[5]*v2.y + c_RH[6]*v3.x + c_RH[7]*v3.y;
    } else {
#pragma unroll
      for (int j = 0; j < 8; ++j) {
        float v = s2[reflect_idx(2 * k + 1 - j, 2053)];
        lo += c_DL[j] * v; hi += c_DH[j] * v;
      }
    }
    d3o[(size_t)r * 1030 + k] = hi;
    s3[k] = lo;
  }
  __syncthreads();

  // level 4: n=1030 -> m=518, transposed scatter (merged in per-XCD L2)
  for (int k = tid; k < 518; k += 256) {
    float lo = 0.f, hi = 0.f;
    if (k >= 3 && k <= 514) {
      const float2* p = (const float2*)&s3[2 * k - 6];
      float2 v0 = p[0], v1 = p[1], v2 = p[2], v3 = p[3];
      lo = c_RL[0]*v0.x + c_RL[1]*v0.y + c_RL[2]*v1.x + c_RL[3]*v1.y +
           c_RL[4]*v2.x + c_RL[5]*v2.y + c_RL[6]*v3.x + c_RL[7]*v3.y;
      hi = c_RH[0]*v0.x + c_RH[1]*v0.y + c_RH[2]*v1.x + c_RH[3]*v1.y +
           c_RH[4]*v2.x + c_RH[5]*v2.y + c_RH[6]*v3.x + c_RH[7]*v3.y;
    } else {
#pragma unroll
      for (int j = 0; j < 8; ++j) {
        float v = s3[reflect_idx(2 * k + 1 - j, 1030)];
        lo += c_DL[j] * v; hi += c_DH[j] * v;
      }
    }
    a4o[(size_t)k * 2048 + s] = lo;
    d4o[(size_t)k * 2048 + s] = hi;
  }
}

// ---------------- Channel mixing v5: one block per (p, a-or-d).
// All staging reads are CONTIGUOUS (weights pre-transposed to wt[p][i*64+o],
// acts written transposed a4t[p][i*32+b] by k_ana234). Everything read once.
__global__ __launch_bounds__(256) void k_mix_pc(const float* __restrict__ wt1,
                                                const float* __restrict__ wt2,
                                                const float* __restrict__ a4t,
                                                const float* __restrict__ d4t,
                                                float* __restrict__ am,
                                                float* __restrict__ dm) {
  // bijective bx -> p with xcd = bx%8 owning contiguous p range (518 = 6*65 + 2*64)
  const int bx = blockIdx.x;
  const int xcd = bx & 7;
  const int j = bx >> 3;
  const int p = (xcd < 6) ? (xcd * 65 + j) : (390 + (xcd - 6) * 64 + j);

  const float* w = blockIdx.y ? wt2 : wt1;
  const float* act = blockIdx.y ? d4t : a4t;
  float* outp = blockIdx.y ? dm : am;

  __shared__ float ws[4096];   // ws[i*64+o]
  __shared__ float as_[2048];  // as_[i*32+b]
  const int tid = threadIdx.x;

  const float4* wg = (const float4*)(w + (size_t)p * 4096);
  const float4* ag = (const float4*)(act + (size_t)p * 2048);
  float4* ws4 = (float4*)ws;
  float4* as4 = (float4*)as_;
  for (int t = tid; t < 1024; t += 256) ws4[t] = wg[t];
  for (int t = tid; t < 512; t += 256) as4[t] = ag[t];
  __syncthreads();

  const int o0 = (tid & 15) * 4;
  const int bq = tid >> 4;  // 0..15 ; batches {bq, bq+16}
  floatx4 acc0 = {0.f, 0.f, 0.f, 0.f}, acc1 = {0.f, 0.f, 0.f, 0.f};

#pragma unroll 8
  for (int i = 0; i < 64; ++i) {
    floatx4 wv = *(const floatx4*)&ws[i * 64 + o0];
    float a0 = as_[i * 32 + bq];
    float a1 = as_[i * 32 + bq + 16];
#pragma unroll
    for (int q = 0; q < 4; ++q) {
      acc0[q] += a0 * wv[q];
      acc1[q] += a1 * wv[q];
    }
  }

#pragma unroll
  for (int q = 0; q < 4; ++q) {
    outp[(size_t)(bq * 64 + o0 + q) * 518 + p] = acc0[q];
    outp[(size_t)((bq + 16) * 64 + o0 + q) * 518 + p] = acc1[q];
  }
}

// ---------------- Fused synthesis: idwt level4->r3, then level3 -> recon2 (bf16)
__global__ __launch_bounds__(256) void k_syn32(const float* __restrict__ a4m,
                                               const float* __restrict__ d4m,
                                               const float* __restrict__ d3,
                                               __hip_bfloat16* __restrict__ r2out) {
  const int r = blockIdx.x;
  const int tid = threadIdx.x;
  __shared__ float sa[518], sd[518], s3d[1030], r3[1030];
  for (int i = tid; i < 518; i += 256) {
    sa[i] = a4m[(size_t)r * 518 + i];
    sd[i] = d4m[(size_t)r * 518 + i];
  }
  for (int i = tid; i < 1030; i += 256) s3d[i] = d3[(size_t)r * 1030 + i];
  __syncthreads();
  for (int s = tid; s < 1030; s += 256) {
    int u = s >> 1, par = s & 1;
    float acc = 0.f;
#pragma unroll
    for (int t = 0; t < 4; ++t) {
      int i = u + 3 - t;
      float fl = par ? c_RL[2 * t + 1] : c_RL[2 * t];
      float fh = par ? c_RH[2 * t + 1] : c_RH[2 * t];
      acc += fl * sa[i] + fh * sd[i];
    }
    r3[s] = acc;
  }
  __syncthreads();
  for (int s = tid; s < 2053; s += 256) {
    int u = s >> 1, par = s & 1;
    float acc = 0.f;
#pragma unroll
    for (int t = 0; t < 4; ++t) {
      int i = u + 3 - t;
      float fl = par ? c_RL[2 * t + 1] : c_RL[2 * t];
      float fh = par ? c_RH[2 * t + 1] : c_RH[2 * t];
      acc += fl * r3[i] + fh * s3d[i];
    }
    r2out[(size_t)r * S2R + s] = __float2bfloat16(acc);
  }
}

// ---------------- Generic IDWT level with strides (used for level 2 -> recon1)
template <typename TCa, typename TCd, typename TOut>
__global__ void k_idwt(const TCa* __restrict__ ca, const TCd* __restrict__ cd,
                       TOut* __restrict__ out, int m, int out_len, int sin, int sout) {
  int s = blockIdx.x * blockDim.x + threadIdx.x;
  if (s >= out_len) return;
  const TCa* pa = ca + (size_t)blockIdx.y * sin;
  const TCd* pd = cd + (size_t)blockIdx.y * sin;
  int u = s >> 1, par = s & 1;
  float acc = 0.f;
#pragma unroll
  for (int t = 0; t < 4; ++t) {
    int i = u + 3 - t;
    float fl = par ? c_RL[2 * t + 1] : c_RL[2 * t];
    float fh = par ? c_RH[2 * t + 1] : c_RH[2 * t];
    acc += fl * ldf(pa, i) + fh * ldf(pd, i);
  }
  stf(out, (size_t)blockIdx.y * sout + s, acc);
}

// ---------------- Epilogue: MFMA dense shortcut + final IDWT + bias + mish -> fp32
// block 256 (4 waves), tile 64n x 64o, grid (128, 32)
__global__ __launch_bounds__(256) void k_epilogue(const __hip_bfloat16* __restrict__ r1,
                                                  const __hip_bfloat16* __restrict__ dd1,
                                                  const float* __restrict__ x,
                                                  const float* __restrict__ dk,
                                                  const float* __restrict__ bias,
                                                  float* __restrict__ out) {
  const int b = blockIdx.y;
  const int n0 = blockIdx.x * 64;
  const int u0 = n0 >> 1;
  const int tid = threadIdx.x;
  const int lane = tid & 63;
  const int w = tid >> 6;

  __shared__ __hip_bfloat16 Kt[64 * 72];  // Kt[o][c], row pad to 72 (144B, 16B-aligned rows)
  __shared__ float ra[35 * 65];
  __shared__ float rd[35 * 65];

  // stage Kt = K^T (bf16)
  {
    const float4* dk4 = (const float4*)dk;
    for (int idx = tid; idx < 1024; idx += 256) {
      int c = idx >> 4, o0 = (idx & 15) * 4;
      float4 v = dk4[idx];  // dk[c][o0..o0+3]
      Kt[(o0 + 0) * 72 + c] = __float2bfloat16(v.x);
      Kt[(o0 + 1) * 72 + c] = __float2bfloat16(v.y);
      Kt[(o0 + 2) * 72 + c] = __float2bfloat16(v.z);
      Kt[(o0 + 3) * 72 + c] = __float2bfloat16(v.w);
    }
  }
  // stage ra/rd (35 coeffs x 64 channels)
  {
    int o2 = tid >> 2;
    const __hip_bfloat16* pr = r1 + (size_t)(b * 64 + o2) * S1R + u0;
    const __hip_bfloat16* pd = dd1 + (size_t)(b * 64 + o2) * S1R + u0;
    for (int il = (tid & 3); il < 35; il += 4) {
      ra[il * 65 + o2] = __bfloat162float(pr[il]);
      rd[il * 65 + o2] = __bfloat162float(pd[il]);
    }
  }
  __syncthreads();

  const int m16 = lane & 15;        // A-row within 16-tile / B-col within o-tile
  const int kq = (lane >> 4) * 8;   // k sub-offset
  const int nrow = w * 16 + m16;    // this lane's A row (n_loc) for loading
  const float* xrow = x + ((size_t)b * 8192 + n0 + nrow) * 64;

  floatx4 acc[4];
#pragma unroll
  for (int ot = 0; ot < 4; ++ot) acc[ot] = (floatx4){0.f, 0.f, 0.f, 0.f};

#pragma unroll
  for (int ks = 0; ks < 2; ++ks) {
    float4 xa = *(const float4*)(xrow + ks * 32 + kq);
    float4 xb = *(const float4*)(xrow + ks * 32 + kq + 4);
    short8 af;
    af[0] = f2bs(xa.x); af[1] = f2bs(xa.y); af[2] = f2bs(xa.z); af[3] = f2bs(xa.w);
    af[4] = f2bs(xb.x); af[5] = f2bs(xb.y); af[6] = f2bs(xb.z); af[7] = f2bs(xb.w);
#pragma unroll
    for (int ot = 0; ot < 4; ++ot) {
      short8 bf = *(const short8*)&Kt[(ot * 16 + m16) * 72 + ks * 32 + kq];
      acc[ot] = __builtin_amdgcn_mfma_f32_16x16x32_bf16(af, bf, acc[ot], 0, 0, 0);
    }
  }

  // epilogue: C/D layout col=lane&15 (o), row=(lane>>4)*4+reg (n)
  const int rbase = (lane >> 4) * 4;
#pragma unroll
  for (int ot = 0; ot < 4; ++ot) {
    int o_loc = ot * 16 + m16;
    float bo = bias[o_loc];
#pragma unroll
    for (int rg = 0; rg < 4; ++rg) {
      int n_loc = w * 16 + rbase + rg;
      int ul = n_loc >> 1, par = n_loc & 1;
      float wv = 0.f;
#pragma unroll
      for (int t = 0; t < 4; ++t) {
        int i = ul + 3 - t;
        float fl = par ? c_RL[2 * t + 1] : c_RL[2 * t];
        float fh = par ? c_RH[2 * t + 1] : c_RH[2 * t];
        wv += fl * ra[i * 65 + o_loc] + fh * rd[i * 65 + o_loc];
      }
      float v = acc[ot][rg] + wv + bo;
      float e = __expf(fminf(v, 15.f));
      float num = e * (e + 2.f);
      float mm = (v > 15.f) ? v : v * (num / (num + 2.f));
      out[((size_t)b * 8192 + n0 + n_loc) * 64 + o_loc] = mm;
    }
  }
}

// ---------------- host ----------------
extern "C" void kernel_launch(void* const* d_in, const int* in_sizes, int n_in,
                              void* d_out, int out_size, void* d_ws, size_t ws_size,
                              hipStream_t stream) {
  const float* x    = (const float*)d_in[0];
  const float* w1   = (const float*)d_in[1];
  const float* w2   = (const float*)d_in[2];
  const float* dk   = (const float*)d_in[3];
  const float* bias = (const float*)d_in[4];
  float* out = (float*)d_out;

  const size_t R = 2048;

  float* wf = (float*)d_ws;
  float* d3f = wf; wf += R * 1030;
  float* a4t = wf; wf += R * 518;   // transposed: [p][i*32+b]
  float* d4t = wf; wf += R * 518;
  float* a4m = wf; wf += R * 518;   // mix outputs, row-major (b*64+o)
  float* d4m = wf; wf += R * 518;
  float* wt1 = wf; wf += (size_t)518 * 4096;  // transposed weights [p][i*64+o]
  float* wt2 = wf; wf += (size_t)518 * 4096;
  __hip_bfloat16* wb = (__hip_bfloat16*)wf;
  __hip_bfloat16* a1b = wb; wb += R * S1R;  // analysis a1, later recon1
  __hip_bfloat16* d1b = wb; wb += R * S1R;
  __hip_bfloat16* a2b = wb; wb += R * S2R;  // analysis a2 unused; holds recon2
  __hip_bfloat16* d2b = wb; wb += R * S2R;
  // total ~92.8 MB

  k_wT<<<dim3(64, 9, 2), 256, 0, stream>>>(w1, w2, wt1, wt2);
  k_dwt_first<<<dim3(65, 32), 256, 0, stream>>>(x, a1b, d1b);
  k_ana234<<<dim3(2048), 256, 0, stream>>>(a1b, d2b, d3f, a4t, d4t);
  k_mix_pc<<<dim3(518, 2), 256, 0, stream>>>(wt1, wt2, a4t, d4t, a4m, d4m);
  k_syn32<<<dim3(2048), 256, 0, stream>>>(a4m, d4m, d3f, a2b);
  k_idwt<__hip_bfloat16, __hip_bfloat16, __hip_bfloat16>
      <<<dim3((4099 + 255) / 256, 2048), 256, 0, stream>>>(a2b, d2b, a1b, 2053, 4099, S2R, S1R);
  k_epilogue<<<dim3(128, 32), 256, 0, stream>>>(a1b, d1b, x, dk, bias, out);
}

// Round 5
// 251.906 us; speedup vs baseline: 1.2051x; 1.1318x over previous
//
#include <hip/hip_runtime.h>
#include <hip/hip_bf16.h>
#include <stdint.h>

typedef __attribute__((ext_vector_type(8))) short short8;
typedef __attribute__((ext_vector_type(4))) float floatx4;

// ---------------- db4 filter constants ----------------
__device__ __constant__ float c_DL[8] = {
    -0.010597401784997278f, 0.032883011666982945f, 0.030841381835986965f,
    -0.18703481171888114f, -0.02798376941698385f, 0.6308807679295904f,
    0.7148465705525415f, 0.23037781330885523f};
__device__ __constant__ float c_DH[8] = {
    -0.23037781330885523f, 0.7148465705525415f, -0.6308807679295904f,
    -0.02798376941698385f, 0.18703481171888114f, 0.030841381835986965f,
    -0.032883011666982945f, -0.010597401784997278f};
// REC_LO = reverse(DEC_LO) (also used as reversed-order analysis lowpass)
__device__ __constant__ float c_RL[8] = {
    0.23037781330885523f, 0.7148465705525415f, 0.6308807679295904f,
    -0.02798376941698385f, -0.18703481171888114f, 0.030841381835986965f,
    0.032883011666982945f, -0.010597401784997278f};
__device__ __constant__ float c_RH[8] = {
    -0.010597401784997278f, -0.032883011666982945f, 0.030841381835986965f,
    0.18703481171888114f, -0.02798376941698385f, -0.6308807679295904f,
    0.7148465705525415f, -0.23037781330885523f};

__device__ __forceinline__ float bflo(uint32_t u) { return __uint_as_float(u << 16); }
__device__ __forceinline__ float bfhi(uint32_t u) { return __uint_as_float(u & 0xffff0000u); }
__device__ __forceinline__ float bfu(unsigned short u) { return __uint_as_float(((uint32_t)u) << 16); }
__device__ __forceinline__ short f2bs(float f) {
  __hip_bfloat16 h = __float2bfloat16(f);
  return *reinterpret_cast<short*>(&h);
}

__device__ __forceinline__ int reflect_idx(int t, int n) {
  if (t < 0) t = -1 - t;
  if (t >= n) t = 2 * n - 1 - t;
  return t;
}

// Row strides (padded for aligned vector access)
#define S1R 4100
#define S2R 2056

// ---------------- Weight transpose: w[i][o][p] -> wt[p][i*64+o]
__global__ __launch_bounds__(256) void k_wT(const float* __restrict__ w1,
                                            const float* __restrict__ w2,
                                            float* __restrict__ wt1,
                                            float* __restrict__ wt2) {
  const float* w = blockIdx.z ? w2 : w1;
  float* wt = blockIdx.z ? wt2 : wt1;
  const int io0 = blockIdx.x * 64;
  const int p0 = blockIdx.y * 64;
  const int pw = min(64, 518 - p0);
  const int tid = threadIdx.x;
  __shared__ float ts[64 * 65];
  for (int idx = tid; idx < 64 * 64; idx += 256) {
    int row = idx >> 6, col = idx & 63;
    if (col < pw) ts[row * 65 + col] = w[(size_t)(io0 + row) * 518 + p0 + col];
  }
  __syncthreads();
  for (int idx = tid; idx < 64 * 64; idx += 256) {
    int pl = idx >> 6, io = idx & 63;
    if (pl < pw) wt[(size_t)(p0 + pl) * 4096 + io0 + io] = ts[io * 65 + pl];
  }
}

// ---------------- Level-1 DWT: x (B,N,C) fp32, transposed read -> a1,d1 (B*C, stride 4100) bf16
#define NT1 134
__global__ __launch_bounds__(256) void k_dwt_first(const float* __restrict__ x,
                                                   __hip_bfloat16* __restrict__ outa,
                                                   __hip_bfloat16* __restrict__ outd) {
  const int b = blockIdx.y;
  const int k0 = blockIdx.x * 64;
  const int tid = threadIdx.x;
  __shared__ float xs[NT1 * 65];

  const float4* x4 = (const float4*)x;
  for (int idx = tid; idx < NT1 * 16; idx += 256) {
    int nl = idx >> 4, cq = idx & 15;
    int t = 2 * k0 - 6 + nl;
    int n = reflect_idx(t, 8192);
    float4 v = x4[((size_t)b * 8192 + n) * 16 + cq];
    float* d = &xs[nl * 65 + 4 * cq];
    d[0] = v.x; d[1] = v.y; d[2] = v.z; d[3] = v.w;
  }
  __syncthreads();

  const int kk = tid & 63;
  const int k = k0 + kk;
  if (k >= 4099) return;
  for (int c = (tid >> 6); c < 64; c += 4) {
    float lo = 0.f, hi = 0.f;
#pragma unroll
    for (int j = 0; j < 8; ++j) {
      float v = xs[(2 * kk + 7 - j) * 65 + c];
      lo += c_DL[j] * v;
      hi += c_DH[j] * v;
    }
    size_t s = (size_t)b * 64 + c;
    outa[s * S1R + k] = __float2bfloat16(lo);
    outd[s * S1R + k] = __float2bfloat16(hi);
  }
}

// ---------------- Fused analysis levels 2..4, one row per block
// Level-4 outputs written TRANSPOSED: a4t[k*2048 + s], s = i*32 + b.
__global__ __launch_bounds__(256) void k_ana234(const __hip_bfloat16* __restrict__ a1,
                                                __hip_bfloat16* __restrict__ d2o,
                                                float* __restrict__ d3o,
                                                float* __restrict__ a4o,
                                                float* __restrict__ d4o) {
  const int bid = blockIdx.x;
  const int s = (bid & 7) * 256 + (bid >> 3);  // bijective, XCD-contiguous s-range
  const int i_ch = s >> 5;                     // input channel 0..63
  const int bb = s & 31;                       // batch 0..31
  const int r = bb * 64 + i_ch;                // row in a1/d2/d3 layouts
  const int tid = threadIdx.x;
  __shared__ float s1[4100];
  __shared__ float s2[2054];
  __shared__ float s3[1032];

  const uint2* row2 = (const uint2*)(a1 + (size_t)r * S1R);
  for (int i = tid; i < 1025; i += 256) {
    uint2 u = row2[i];
    int e = 4 * i;
    s1[e] = bflo(u.x); s1[e + 1] = bfhi(u.x);
    s1[e + 2] = bflo(u.y); s1[e + 3] = bfhi(u.y);
  }
  __syncthreads();

  // level 2: n=4099 -> m=2053
  for (int k = tid; k < 2053; k += 256) {
    float lo = 0.f, hi = 0.f;
    if (k >= 3 && k <= 2048) {
      const float2* p = (const float2*)&s1[2 * k - 6];
      float2 v0 = p[0], v1 = p[1], v2 = p[2], v3 = p[3];
      lo = c_RL[0]*v0.x + c_RL[1]*v0.y + c_RL[2]*v1.x + c_RL[3]*v1.y +
           c_RL[4]*v2.x + c_RL[5]*v2.y + c_RL[6]*v3.x + c_RL[7]*v3.y;
      hi = c_RH[0]*v0.x + c_RH[1]*v0.y + c_RH[2]*v1.x + c_RH[3]*v1.y +
           c_RH[4]*v2.x + c_RH[5]*v2.y + c_RH[6]*v3.x + c_RH[7]*v3.y;
    } else {
#pragma unroll
      for (int j = 0; j < 8; ++j) {
        float v = s1[reflect_idx(2 * k + 1 - j, 4099)];
        lo += c_DL[j] * v; hi += c_DH[j] * v;
      }
    }
    d2o[(size_t)r * S2R + k] = __float2bfloat16(hi);
    s2[k] = lo;
  }
  __syncthreads();

  // level 3: n=2053 -> m=1030
  for (int k = tid; k < 1030; k += 256) {
    float lo = 0.f, hi = 0.f;
    if (k >= 3 && k <= 1025) {
      const float2* p = (const float2*)&s2[2 * k - 6];
      float2 v0 = p[0], v1 = p[1], v2 = p[2], v3 = p[3];
      lo = c_RL[0]*v0.x + c_RL[1]*v0.y + c_RL[2]*v1.x + c_RL[3]*v1.y +
           c_RL[4]*v2.x + c_RL[5]*v2.y + c_RL[6]*v3.x + c_RL[7]*v3.y;
      hi = c_RH[0]*v0.x + c_RH[1]*v0.y + c_RH[2]*v1.x + c_RH[3]*v1.y +
           c_RH[4]*v2.x + c_RH[5]*v2.y + c_RH[6]*v3.x + c_RH[7]*v3.y;
    } else {
#pragma unroll
      for (int j = 0; j < 8; ++j) {
        float v = s2[reflect_idx(2 * k + 1 - j, 2053)];
        lo += c_DL[j] * v; hi += c_DH[j] * v;
      }
    }
    d3o[(size_t)r * 1030 + k] = hi;
    s3[k] = lo;
  }
  __syncthreads();

  // level 4: n=1030 -> m=518, transposed scatter (merged in per-XCD L2)
  for (int k = tid; k < 518; k += 256) {
    float lo = 0.f, hi = 0.f;
    if (k >= 3 && k <= 514) {
      const float2* p = (const float2*)&s3[2 * k - 6];
      float2 v0 = p[0], v1 = p[1], v2 = p[2], v3 = p[3];
      lo = c_RL[0]*v0.x + c_RL[1]*v0.y + c_RL[2]*v1.x + c_RL[3]*v1.y +
           c_RL[4]*v2.x + c_RL[5]*v2.y + c_RL[6]*v3.x + c_RL[7]*v3.y;
      hi = c_RH[0]*v0.x + c_RH[1]*v0.y + c_RH[2]*v1.x + c_RH[3]*v1.y +
           c_RH[4]*v2.x + c_RH[5]*v2.y + c_RH[6]*v3.x + c_RH[7]*v3.y;
    } else {
#pragma unroll
      for (int j = 0; j < 8; ++j) {
        float v = s3[reflect_idx(2 * k + 1 - j, 1030)];
        lo += c_DL[j] * v; hi += c_DH[j] * v;
      }
    }
    a4o[(size_t)k * 2048 + s] = lo;
    d4o[(size_t)k * 2048 + s] = hi;
  }
}

// ---------------- Channel mixing: one block per (p, a-or-d), all staging contiguous.
__global__ __launch_bounds__(256) void k_mix_pc(const float* __restrict__ wt1,
                                                const float* __restrict__ wt2,
                                                const float* __restrict__ a4t,
                                                const float* __restrict__ d4t,
                                                float* __restrict__ am,
                                                float* __restrict__ dm) {
  // bijective bx -> p with xcd = bx%8 owning contiguous p range (518 = 6*65 + 2*64)
  const int bx = blockIdx.x;
  const int xcd = bx & 7;
  const int j = bx >> 3;
  const int p = (xcd < 6) ? (xcd * 65 + j) : (390 + (xcd - 6) * 64 + j);

  const float* w = blockIdx.y ? wt2 : wt1;
  const float* act = blockIdx.y ? d4t : a4t;
  float* outp = blockIdx.y ? dm : am;

  __shared__ float ws[4096];   // ws[i*64+o]
  __shared__ float as_[2048];  // as_[i*32+b]
  const int tid = threadIdx.x;

  const float4* wg = (const float4*)(w + (size_t)p * 4096);
  const float4* ag = (const float4*)(act + (size_t)p * 2048);
  float4* ws4 = (float4*)ws;
  float4* as4 = (float4*)as_;
  for (int t = tid; t < 1024; t += 256) ws4[t] = wg[t];
  for (int t = tid; t < 512; t += 256) as4[t] = ag[t];
  __syncthreads();

  const int o0 = (tid & 15) * 4;
  const int bq = tid >> 4;  // 0..15 ; batches {bq, bq+16}
  floatx4 acc0 = {0.f, 0.f, 0.f, 0.f}, acc1 = {0.f, 0.f, 0.f, 0.f};

#pragma unroll 8
  for (int i = 0; i < 64; ++i) {
    floatx4 wv = *(const floatx4*)&ws[i * 64 + o0];
    float a0 = as_[i * 32 + bq];
    float a1 = as_[i * 32 + bq + 16];
#pragma unroll
    for (int q = 0; q < 4; ++q) {
      acc0[q] += a0 * wv[q];
      acc1[q] += a1 * wv[q];
    }
  }

#pragma unroll
  for (int q = 0; q < 4; ++q) {
    outp[(size_t)(bq * 64 + o0 + q) * 518 + p] = acc0[q];
    outp[(size_t)((bq + 16) * 64 + o0 + q) * 518 + p] = acc1[q];
  }
}

// ---------------- Fused synthesis levels 4->3->2: writes recon1 (bf16) directly.
// One row per block; r2 kept fp32 in LDS (no bf16 round-trip through HBM).
__global__ __launch_bounds__(256) void k_syn(const float* __restrict__ a4m,
                                             const float* __restrict__ d4m,
                                             const float* __restrict__ d3,
                                             const __hip_bfloat16* __restrict__ d2,
                                             __hip_bfloat16* __restrict__ r1out) {
  const int r = blockIdx.x;
  const int tid = threadIdx.x;
  __shared__ float sa[518], sd[518], s3d[1030], r3[1030], d2s[2056], r2[2053];
  for (int i = tid; i < 518; i += 256) {
    sa[i] = a4m[(size_t)r * 518 + i];
    sd[i] = d4m[(size_t)r * 518 + i];
  }
  for (int i = tid; i < 1030; i += 256) s3d[i] = d3[(size_t)r * 1030 + i];
  {
    const uint2* p2 = (const uint2*)(d2 + (size_t)r * S2R);
    for (int i = tid; i < 514; i += 256) {
      uint2 u = p2[i];
      int e = 4 * i;
      d2s[e] = bflo(u.x); d2s[e + 1] = bfhi(u.x);
      d2s[e + 2] = bflo(u.y); d2s[e + 3] = bfhi(u.y);
    }
  }
  __syncthreads();
  // level 4 -> r3 (1030)
  for (int s = tid; s < 1030; s += 256) {
    int u = s >> 1, par = s & 1;
    float acc = 0.f;
#pragma unroll
    for (int t = 0; t < 4; ++t) {
      int i = u + 3 - t;
      float fl = par ? c_RL[2 * t + 1] : c_RL[2 * t];
      float fh = par ? c_RH[2 * t + 1] : c_RH[2 * t];
      acc += fl * sa[i] + fh * sd[i];
    }
    r3[s] = acc;
  }
  __syncthreads();
  // level 3 -> r2 (2053), fp32 in LDS
  for (int s = tid; s < 2053; s += 256) {
    int u = s >> 1, par = s & 1;
    float acc = 0.f;
#pragma unroll
    for (int t = 0; t < 4; ++t) {
      int i = u + 3 - t;
      float fl = par ? c_RL[2 * t + 1] : c_RL[2 * t];
      float fh = par ? c_RH[2 * t + 1] : c_RH[2 * t];
      acc += fl * r3[i] + fh * s3d[i];
    }
    r2[s] = acc;
  }
  __syncthreads();
  // level 2 -> r1 (4099), bf16 to global
  for (int s = tid; s < 4099; s += 256) {
    int u = s >> 1, par = s & 1;
    float acc = 0.f;
#pragma unroll
    for (int t = 0; t < 4; ++t) {
      int i = u + 3 - t;
      float fl = par ? c_RL[2 * t + 1] : c_RL[2 * t];
      float fh = par ? c_RH[2 * t + 1] : c_RH[2 * t];
      acc += fl * r2[i] + fh * d2s[i];
    }
    r1out[(size_t)r * S1R + s] = __float2bfloat16(acc);
  }
}

// ---------------- Epilogue: MFMA dense shortcut + final IDWT + bias + mish -> fp32
// block 256 (4 waves), tile 64n x 64o, grid (128, 32)
// ra/rd stride 68: bank = (4i+o)%32; i-groups offset {0,8,16,24} -> 2-way (free).
#define RAS 68
__global__ __launch_bounds__(256) void k_epilogue(const __hip_bfloat16* __restrict__ r1,
                                                  const __hip_bfloat16* __restrict__ dd1,
                                                  const float* __restrict__ x,
                                                  const float* __restrict__ dk,
                                                  const float* __restrict__ bias,
                                                  float* __restrict__ out) {
  const int b = blockIdx.y;
  const int n0 = blockIdx.x * 64;
  const int u0 = n0 >> 1;
  const int tid = threadIdx.x;
  const int lane = tid & 63;
  const int w = tid >> 6;

  __shared__ __hip_bfloat16 Kt[64 * 72];  // Kt[o][c], row pad to 72
  __shared__ float ra[36 * RAS];
  __shared__ float rd[36 * RAS];

  // stage Kt = K^T (bf16)
  {
    const float4* dk4 = (const float4*)dk;
    for (int idx = tid; idx < 1024; idx += 256) {
      int c = idx >> 4, o0 = (idx & 15) * 4;
      float4 v = dk4[idx];  // dk[c][o0..o0+3]
      Kt[(o0 + 0) * 72 + c] = __float2bfloat16(v.x);
      Kt[(o0 + 1) * 72 + c] = __float2bfloat16(v.y);
      Kt[(o0 + 2) * 72 + c] = __float2bfloat16(v.z);
      Kt[(o0 + 3) * 72 + c] = __float2bfloat16(v.w);
    }
  }
  // stage ra/rd (35 coeffs x 64 channels), vectorized ushort4 (8B) loads.
  // Row base byte = row*8200 + 64*bx : both 8-aligned.
  {
    int o2 = tid >> 2;
    const ushort4* pr4 = (const ushort4*)(r1 + (size_t)(b * 64 + o2) * S1R + u0);
    const ushort4* pd4 = (const ushort4*)(dd1 + (size_t)(b * 64 + o2) * S1R + u0);
    for (int q = tid & 3; q < 9; q += 4) {
      ushort4 v = pr4[q];
      int i0 = 4 * q;
      ra[(i0 + 0) * RAS + o2] = bfu(v.x);
      ra[(i0 + 1) * RAS + o2] = bfu(v.y);
      ra[(i0 + 2) * RAS + o2] = bfu(v.z);
      ra[(i0 + 3) * RAS + o2] = bfu(v.w);
      ushort4 d = pd4[q];
      rd[(i0 + 0) * RAS + o2] = bfu(d.x);
      rd[(i0 + 1) * RAS + o2] = bfu(d.y);
      rd[(i0 + 2) * RAS + o2] = bfu(d.z);
      rd[(i0 + 3) * RAS + o2] = bfu(d.w);
    }
  }
  __syncthreads();

  const int m16 = lane & 15;        // A-row within 16-tile / B-col within o-tile
  const int kq = (lane >> 4) * 8;   // k sub-offset
  const int nrow = w * 16 + m16;    // this lane's A row (n_loc) for loading
  const float* xrow = x + ((size_t)b * 8192 + n0 + nrow) * 64;

  floatx4 acc[4];
#pragma unroll
  for (int ot = 0; ot < 4; ++ot) acc[ot] = (floatx4){0.f, 0.f, 0.f, 0.f};

#pragma unroll
  for (int ks = 0; ks < 2; ++ks) {
    float4 xa = *(const float4*)(xrow + ks * 32 + kq);
    float4 xb = *(const float4*)(xrow + ks * 32 + kq + 4);
    short8 af;
    af[0] = f2bs(xa.x); af[1] = f2bs(xa.y); af[2] = f2bs(xa.z); af[3] = f2bs(xa.w);
    af[4] = f2bs(xb.x); af[5] = f2bs(xb.y); af[6] = f2bs(xb.z); af[7] = f2bs(xb.w);
#pragma unroll
    for (int ot = 0; ot < 4; ++ot) {
      short8 bf = *(const short8*)&Kt[(ot * 16 + m16) * 72 + ks * 32 + kq];
      acc[ot] = __builtin_amdgcn_mfma_f32_16x16x32_bf16(af, bf, acc[ot], 0, 0, 0);
    }
  }

  // epilogue: C/D layout col=lane&15 (o), row=(lane>>4)*4+reg (n)
  const int rbase = (lane >> 4) * 4;
#pragma unroll
  for (int ot = 0; ot < 4; ++ot) {
    int o_loc = ot * 16 + m16;
    float bo = bias[o_loc];
#pragma unroll
    for (int rg = 0; rg < 4; ++rg) {
      int n_loc = w * 16 + rbase + rg;
      int ul = n_loc >> 1, par = n_loc & 1;
      float wv = 0.f;
#pragma unroll
      for (int t = 0; t < 4; ++t) {
        int i = ul + 3 - t;
        float fl = par ? c_RL[2 * t + 1] : c_RL[2 * t];
        float fh = par ? c_RH[2 * t + 1] : c_RH[2 * t];
        wv += fl * ra[i * RAS + o_loc] + fh * rd[i * RAS + o_loc];
      }
      float v = acc[ot][rg] + wv + bo;
      float e = __expf(fminf(v, 15.f));
      float num = e * (e + 2.f);
      float mm = (v > 15.f) ? v : v * (num / (num + 2.f));
      // out is write-once, never re-read: nontemporal keeps L2/L3 for r1/d1.
      __builtin_nontemporal_store(mm, &out[((size_t)b * 8192 + n0 + n_loc) * 64 + o_loc]);
    }
  }
}

// ---------------- host ----------------
extern "C" void kernel_launch(void* const* d_in, const int* in_sizes, int n_in,
                              void* d_out, int out_size, void* d_ws, size_t ws_size,
                              hipStream_t stream) {
  const float* x    = (const float*)d_in[0];
  const float* w1   = (const float*)d_in[1];
  const float* w2   = (const float*)d_in[2];
  const float* dk   = (const float*)d_in[3];
  const float* bias = (const float*)d_in[4];
  float* out = (float*)d_out;

  const size_t R = 2048;

  float* wf = (float*)d_ws;
  float* d3f = wf; wf += R * 1030;
  float* a4t = wf; wf += R * 518;   // transposed: [p][i*32+b]
  float* d4t = wf; wf += R * 518;
  float* a4m = wf; wf += R * 518;   // mix outputs, row-major (b*64+o)
  float* d4m = wf; wf += R * 518;
  float* wt1 = wf; wf += (size_t)518 * 4096;  // transposed weights [p][i*64+o]
  float* wt2 = wf; wf += (size_t)518 * 4096;
  __hip_bfloat16* wb = (__hip_bfloat16*)wf;
  __hip_bfloat16* a1b = wb; wb += R * S1R;  // analysis a1, later recon1
  __hip_bfloat16* d1b = wb; wb += R * S1R;
  __hip_bfloat16* d2b = wb; wb += R * S2R;

  k_wT<<<dim3(64, 9, 2), 256, 0, stream>>>(w1, w2, wt1, wt2);
  k_dwt_first<<<dim3(65, 32), 256, 0, stream>>>(x, a1b, d1b);
  k_ana234<<<dim3(2048), 256, 0, stream>>>(a1b, d2b, d3f, a4t, d4t);
  k_mix_pc<<<dim3(518, 2), 256, 0, stream>>>(wt1, wt2, a4t, d4t, a4m, d4m);
  k_syn<<<dim3(2048), 256, 0, stream>>>(a4m, d4m, d3f, d2b, a1b);
  k_epilogue<<<dim3(128, 32), 256, 0, stream>>>(a1b, d1b, x, dk, bias, out);
}

// Round 6
// 249.034 us; speedup vs baseline: 1.2190x; 1.0115x over previous
//
#include <hip/hip_runtime.h>
#include <hip/hip_bf16.h>
#include <stdint.h>

typedef __attribute__((ext_vector_type(8))) short short8;
typedef __attribute__((ext_vector_type(4))) float floatx4;

// ---------------- db4 filter constants ----------------
__device__ __constant__ float c_DL[8] = {
    -0.010597401784997278f, 0.032883011666982945f, 0.030841381835986965f,
    -0.18703481171888114f, -0.02798376941698385f, 0.6308807679295904f,
    0.7148465705525415f, 0.23037781330885523f};
__device__ __constant__ float c_DH[8] = {
    -0.23037781330885523f, 0.7148465705525415f, -0.6308807679295904f,
    -0.02798376941698385f, 0.18703481171888114f, 0.030841381835986965f,
    -0.032883011666982945f, -0.010597401784997278f};
// REC_LO = reverse(DEC_LO) (also used as reversed-order analysis lowpass)
__device__ __constant__ float c_RL[8] = {
    0.23037781330885523f, 0.7148465705525415f, 0.6308807679295904f,
    -0.02798376941698385f, -0.18703481171888114f, 0.030841381835986965f,
    0.032883011666982945f, -0.010597401784997278f};
__device__ __constant__ float c_RH[8] = {
    -0.010597401784997278f, -0.032883011666982945f, 0.030841381835986965f,
    0.18703481171888114f, -0.02798376941698385f, -0.6308807679295904f,
    0.7148465705525415f, -0.23037781330885523f};

__device__ __forceinline__ float bflo(uint32_t u) { return __uint_as_float(u << 16); }
__device__ __forceinline__ float bfhi(uint32_t u) { return __uint_as_float(u & 0xffff0000u); }
__device__ __forceinline__ float bfu(unsigned short u) { return __uint_as_float(((uint32_t)u) << 16); }
__device__ __forceinline__ short f2bs(float f) {
  __hip_bfloat16 h = __float2bfloat16(f);
  return *reinterpret_cast<short*>(&h);
}

__device__ __forceinline__ int reflect_idx(int t, int n) {
  if (t < 0) t = -1 - t;
  if (t >= n) t = 2 * n - 1 - t;
  return t;
}

// Row strides (padded for aligned vector access)
#define S1R 4100
#define S2R 2056

// ---------------- Weight transpose: w[i][o][p] -> wt[p][i*64+o]
__global__ __launch_bounds__(256) void k_wT(const float* __restrict__ w1,
                                            const float* __restrict__ w2,
                                            float* __restrict__ wt1,
                                            float* __restrict__ wt2) {
  const float* w = blockIdx.z ? w2 : w1;
  float* wt = blockIdx.z ? wt2 : wt1;
  const int io0 = blockIdx.x * 64;
  const int p0 = blockIdx.y * 64;
  const int pw = min(64, 518 - p0);
  const int tid = threadIdx.x;
  __shared__ float ts[64 * 65];
  for (int idx = tid; idx < 64 * 64; idx += 256) {
    int row = idx >> 6, col = idx & 63;
    if (col < pw) ts[row * 65 + col] = w[(size_t)(io0 + row) * 518 + p0 + col];
  }
  __syncthreads();
  for (int idx = tid; idx < 64 * 64; idx += 256) {
    int pl = idx >> 6, io = idx & 63;
    if (pl < pw) wt[(size_t)(p0 + pl) * 4096 + io0 + io] = ts[io * 65 + pl];
  }
}

// ---------------- Level-1 DWT: x (B,N,C) fp32 -> a1,d1 (B*C, stride 4100) bf16
// xs stored TRANSPOSED xs[c][nrow], stride 138 (=10 mod 32, even for float2 align):
// compute reads are aligned float2, conflict-free; staging writes 4-way (was:
// 128 4-way scalar reads per thread).
#define NT1 134
#define XTS 138
__global__ __launch_bounds__(256) void k_dwt_first(const float* __restrict__ x,
                                                   __hip_bfloat16* __restrict__ outa,
                                                   __hip_bfloat16* __restrict__ outd) {
  const int b = blockIdx.y;
  const int k0 = blockIdx.x * 64;
  const int tid = threadIdx.x;
  __shared__ float xs[64 * XTS];  // xs[c][nrow]

  const float4* x4 = (const float4*)x;
  for (int idx = tid; idx < NT1 * 16; idx += 256) {
    int nl = idx >> 4, cq = idx & 15;
    int t = 2 * k0 - 6 + nl;
    int n = reflect_idx(t, 8192);
    float4 v = x4[((size_t)b * 8192 + n) * 16 + cq];
    xs[(4 * cq + 0) * XTS + nl] = v.x;
    xs[(4 * cq + 1) * XTS + nl] = v.y;
    xs[(4 * cq + 2) * XTS + nl] = v.z;
    xs[(4 * cq + 3) * XTS + nl] = v.w;
  }
  __syncthreads();

  const int kk = tid & 63;
  const int k = k0 + kk;
  if (k >= 4099) return;
  for (int c = (tid >> 6); c < 64; c += 4) {
    const float2* p = (const float2*)&xs[c * XTS + 2 * kk];
    float2 p0 = p[0], p1 = p[1], p2 = p[2], p3 = p[3];
    // original order: j=0..7, v_j = row (2kk+7-j); keep exact accumulation order
    float lo = c_DL[0] * p3.y + c_DL[1] * p3.x + c_DL[2] * p2.y + c_DL[3] * p2.x +
               c_DL[4] * p1.y + c_DL[5] * p1.x + c_DL[6] * p0.y + c_DL[7] * p0.x;
    float hi = c_DH[0] * p3.y + c_DH[1] * p3.x + c_DH[2] * p2.y + c_DH[3] * p2.x +
               c_DH[4] * p1.y + c_DH[5] * p1.x + c_DH[6] * p0.y + c_DH[7] * p0.x;
    size_t s = (size_t)b * 64 + c;
    outa[s * S1R + k] = __float2bfloat16(lo);
    outd[s * S1R + k] = __float2bfloat16(hi);
  }
}

// ---------------- Fused analysis levels 2..4, one row per block
// Level-4 outputs written TRANSPOSED: a4t[k*2048 + s], s = i*32 + b.
__global__ __launch_bounds__(256) void k_ana234(const __hip_bfloat16* __restrict__ a1,
                                                __hip_bfloat16* __restrict__ d2o,
                                                float* __restrict__ d3o,
                                                float* __restrict__ a4o,
                                                float* __restrict__ d4o) {
  const int bid = blockIdx.x;
  const int s = (bid & 7) * 256 + (bid >> 3);  // bijective, XCD-contiguous s-range
  const int i_ch = s >> 5;                     // input channel 0..63
  const int bb = s & 31;                       // batch 0..31
  const int r = bb * 64 + i_ch;                // row in a1/d2/d3 layouts
  const int tid = threadIdx.x;
  __shared__ float s1[4100];
  __shared__ float s2[2054];
  __shared__ float s3[1032];

  const uint2* row2 = (const uint2*)(a1 + (size_t)r * S1R);
  for (int i = tid; i < 1025; i += 256) {
    uint2 u = row2[i];
    int e = 4 * i;
    s1[e] = bflo(u.x); s1[e + 1] = bfhi(u.x);
    s1[e + 2] = bflo(u.y); s1[e + 3] = bfhi(u.y);
  }
  __syncthreads();

  // level 2: n=4099 -> m=2053
  for (int k = tid; k < 2053; k += 256) {
    float lo = 0.f, hi = 0.f;
    if (k >= 3 && k <= 2048) {
      const float2* p = (const float2*)&s1[2 * k - 6];
      float2 v0 = p[0], v1 = p[1], v2 = p[2], v3 = p[3];
      lo = c_RL[0]*v0.x + c_RL[1]*v0.y + c_RL[2]*v1.x + c_RL[3]*v1.y +
           c_RL[4]*v2.x + c_RL[5]*v2.y + c_RL[6]*v3.x + c_RL[7]*v3.y;
      hi = c_RH[0]*v0.x + c_RH[1]*v0.y + c_RH[2]*v1.x + c_RH[3]*v1.y +
           c_RH[4]*v2.x + c_RH[5]*v2.y + c_RH[6]*v3.x + c_RH[7]*v3.y;
    } else {
#pragma unroll
      for (int j = 0; j < 8; ++j) {
        float v = s1[reflect_idx(2 * k + 1 - j, 4099)];
        lo += c_DL[j] * v; hi += c_DH[j] * v;
      }
    }
    d2o[(size_t)r * S2R + k] = __float2bfloat16(hi);
    s2[k] = lo;
  }
  __syncthreads();

  // level 3: n=2053 -> m=1030
  for (int k = tid; k < 1030; k += 256) {
    float lo = 0.f, hi = 0.f;
    if (k >= 3 && k <= 1025) {
      const float2* p = (const float2*)&s2[2 * k - 6];
      float2 v0 = p[0], v1 = p[1], v2 = p[2], v3 = p[3];
      lo = c_RL[0]*v0.x + c_RL[1]*v0.y + c_RL[2]*v1.x + c_RL[3]*v1.y +
           c_RL[4]*v2.x + c_RL[5]*v2.y + c_RL[6]*v3.x + c_RL[7]*v3.y;
      hi = c_RH[0]*v0.x + c_RH[1]*v0.y + c_RH[2]*v1.x + c_RH[3]*v1.y +
           c_RH[4]*v2.x + c_RH[5]*v2.y + c_RH[6]*v3.x + c_RH[7]*v3.y;
    } else {
#pragma unroll
      for (int j = 0; j < 8; ++j) {
        float v = s2[reflect_idx(2 * k + 1 - j, 2053)];
        lo += c_DL[j] * v; hi += c_DH[j] * v;
      }
    }
    d3o[(size_t)r * 1030 + k] = hi;
    s3[k] = lo;
  }
  __syncthreads();

  // level 4: n=1030 -> m=518, transposed scatter (merged in per-XCD L2)
  for (int k = tid; k < 518; k += 256) {
    float lo = 0.f, hi = 0.f;
    if (k >= 3 && k <= 514) {
      const float2* p = (const float2*)&s3[2 * k - 6];
      float2 v0 = p[0], v1 = p[1], v2 = p[2], v3 = p[3];
      lo = c_RL[0]*v0.x + c_RL[1]*v0.y + c_RL[2]*v1.x + c_RL[3]*v1.y +
           c_RL[4]*v2.x + c_RL[5]*v2.y + c_RL[6]*v3.x + c_RL[7]*v3.y;
      hi = c_RH[0]*v0.x + c_RH[1]*v0.y + c_RH[2]*v1.x + c_RH[3]*v1.y +
           c_RH[4]*v2.x + c_RH[5]*v2.y + c_RH[6]*v3.x + c_RH[7]*v3.y;
    } else {
#pragma unroll
      for (int j = 0; j < 8; ++j) {
        float v = s3[reflect_idx(2 * k + 1 - j, 1030)];
        lo += c_DL[j] * v; hi += c_DH[j] * v;
      }
    }
    a4o[(size_t)k * 2048 + s] = lo;
    d4o[(size_t)k * 2048 + s] = hi;
  }
}

// ---------------- Channel mixing: one block per (p, a-or-d), all staging contiguous.
__global__ __launch_bounds__(256) void k_mix_pc(const float* __restrict__ wt1,
                                                const float* __restrict__ wt2,
                                                const float* __restrict__ a4t,
                                                const float* __restrict__ d4t,
                                                float* __restrict__ am,
                                                float* __restrict__ dm) {
  // bijective bx -> p with xcd = bx%8 owning contiguous p range (518 = 6*65 + 2*64)
  const int bx = blockIdx.x;
  const int xcd = bx & 7;
  const int j = bx >> 3;
  const int p = (xcd < 6) ? (xcd * 65 + j) : (390 + (xcd - 6) * 64 + j);

  const float* w = blockIdx.y ? wt2 : wt1;
  const float* act = blockIdx.y ? d4t : a4t;
  float* outp = blockIdx.y ? dm : am;

  __shared__ float ws[4096];   // ws[i*64+o]
  __shared__ float as_[2048];  // as_[i*32+b]
  const int tid = threadIdx.x;

  const float4* wg = (const float4*)(w + (size_t)p * 4096);
  const float4* ag = (const float4*)(act + (size_t)p * 2048);
  float4* ws4 = (float4*)ws;
  float4* as4 = (float4*)as_;
  for (int t = tid; t < 1024; t += 256) ws4[t] = wg[t];
  for (int t = tid; t < 512; t += 256) as4[t] = ag[t];
  __syncthreads();

  const int o0 = (tid & 15) * 4;
  const int bq = tid >> 4;  // 0..15 ; batches {bq, bq+16}
  floatx4 acc0 = {0.f, 0.f, 0.f, 0.f}, acc1 = {0.f, 0.f, 0.f, 0.f};

#pragma unroll 8
  for (int i = 0; i < 64; ++i) {
    floatx4 wv = *(const floatx4*)&ws[i * 64 + o0];
    float a0 = as_[i * 32 + bq];
    float a1 = as_[i * 32 + bq + 16];
#pragma unroll
    for (int q = 0; q < 4; ++q) {
      acc0[q] += a0 * wv[q];
      acc1[q] += a1 * wv[q];
    }
  }

#pragma unroll
  for (int q = 0; q < 4; ++q) {
    outp[(size_t)(bq * 64 + o0 + q) * 518 + p] = acc0[q];
    outp[(size_t)((bq + 16) * 64 + o0 + q) * 518 + p] = acc1[q];
  }
}

// ---------------- Fused synthesis levels 4->3->2: writes recon1 (bf16) directly.
__global__ __launch_bounds__(256) void k_syn(const float* __restrict__ a4m,
                                             const float* __restrict__ d4m,
                                             const float* __restrict__ d3,
                                             const __hip_bfloat16* __restrict__ d2,
                                             __hip_bfloat16* __restrict__ r1out) {
  const int r = blockIdx.x;
  const int tid = threadIdx.x;
  __shared__ float sa[518], sd[518], s3d[1030], r3[1030], d2s[2056], r2[2053];
  for (int i = tid; i < 518; i += 256) {
    sa[i] = a4m[(size_t)r * 518 + i];
    sd[i] = d4m[(size_t)r * 518 + i];
  }
  for (int i = tid; i < 1030; i += 256) s3d[i] = d3[(size_t)r * 1030 + i];
  {
    const uint2* p2 = (const uint2*)(d2 + (size_t)r * S2R);
    for (int i = tid; i < 514; i += 256) {
      uint2 u = p2[i];
      int e = 4 * i;
      d2s[e] = bflo(u.x); d2s[e + 1] = bfhi(u.x);
      d2s[e + 2] = bflo(u.y); d2s[e + 3] = bfhi(u.y);
    }
  }
  __syncthreads();
  // level 4 -> r3 (1030)
  for (int s = tid; s < 1030; s += 256) {
    int u = s >> 1, par = s & 1;
    float acc = 0.f;
#pragma unroll
    for (int t = 0; t < 4; ++t) {
      int i = u + 3 - t;
      float fl = par ? c_RL[2 * t + 1] : c_RL[2 * t];
      float fh = par ? c_RH[2 * t + 1] : c_RH[2 * t];
      acc += fl * sa[i] + fh * sd[i];
    }
    r3[s] = acc;
  }
  __syncthreads();
  // level 3 -> r2 (2053), fp32 in LDS
  for (int s = tid; s < 2053; s += 256) {
    int u = s >> 1, par = s & 1;
    float acc = 0.f;
#pragma unroll
    for (int t = 0; t < 4; ++t) {
      int i = u + 3 - t;
      float fl = par ? c_RL[2 * t + 1] : c_RL[2 * t];
      float fh = par ? c_RH[2 * t + 1] : c_RH[2 * t];
      acc += fl * r3[i] + fh * s3d[i];
    }
    r2[s] = acc;
  }
  __syncthreads();
  // level 2 -> r1 (4099), bf16 to global
  for (int s = tid; s < 4099; s += 256) {
    int u = s >> 1, par = s & 1;
    float acc = 0.f;
#pragma unroll
    for (int t = 0; t < 4; ++t) {
      int i = u + 3 - t;
      float fl = par ? c_RL[2 * t + 1] : c_RL[2 * t];
      float fh = par ? c_RH[2 * t + 1] : c_RH[2 * t];
      acc += fl * r2[i] + fh * d2s[i];
    }
    r1out[(size_t)r * S1R + s] = __float2bfloat16(acc);
  }
}

// ---------------- Epilogue: MFMA dense shortcut + final IDWT + bias + mish -> fp32
// block 256 (4 waves), tile 64n x 64o, grid (128, 32)
// Ktf is FRAGMENT-ORDERED: b128 lane-contiguous reads AND b128 staging writes
// (was: 16-way-conflicted scalar bf16 staging writes = dominant conflict source).
#define RAS 68
__global__ __launch_bounds__(256) void k_epilogue(const __hip_bfloat16* __restrict__ r1,
                                                  const __hip_bfloat16* __restrict__ dd1,
                                                  const float* __restrict__ x,
                                                  const float* __restrict__ dk,
                                                  const float* __restrict__ bias,
                                                  float* __restrict__ out) {
  const int b = blockIdx.y;
  const int n0 = blockIdx.x * 64;
  const int u0 = n0 >> 1;
  const int tid = threadIdx.x;
  const int lane = tid & 63;
  const int w = tid >> 6;

  __shared__ __hip_bfloat16 Ktf[4096];  // [(ot*2+ks)*64 + lane]*8 fragment order
  __shared__ float ra[36 * RAS];
  __shared__ float rd[36 * RAS];

  // stage Ktf: thread t owns column o=t&63; (ks,hi) slot = (t>>6)+4*it.
  // Global reads: 16 stride-256B scalar loads, each wave-coalesced (o consecutive).
  // LDS writes: b128 per fragment, start banks 4*(l&15) -> 2-way (free).
  {
    int o = tid & 63;
    int ot = o >> 4, m16 = o & 15;
    for (int it = 0; it < 2; ++it) {
      int slot = (tid >> 6) + 4 * it;
      int ks = slot >> 2, hi = slot & 3;
      int c0 = ks * 32 + hi * 8;
      short8 f;
#pragma unroll
      for (int kq2 = 0; kq2 < 8; ++kq2)
        f[kq2] = f2bs(dk[(size_t)(c0 + kq2) * 64 + o]);
      *(short8*)&Ktf[((ot * 2 + ks) * 64 + hi * 16 + m16) * 8] = f;
    }
  }
  // stage ra/rd (35 coeffs x 64 channels), vectorized ushort4 (8B) loads.
  {
    int o2 = tid >> 2;
    const ushort4* pr4 = (const ushort4*)(r1 + (size_t)(b * 64 + o2) * S1R + u0);
    const ushort4* pd4 = (const ushort4*)(dd1 + (size_t)(b * 64 + o2) * S1R + u0);
    for (int q = tid & 3; q < 9; q += 4) {
      ushort4 v = pr4[q];
      int i0 = 4 * q;
      ra[(i0 + 0) * RAS + o2] = bfu(v.x);
      ra[(i0 + 1) * RAS + o2] = bfu(v.y);
      ra[(i0 + 2) * RAS + o2] = bfu(v.z);
      ra[(i0 + 3) * RAS + o2] = bfu(v.w);
      ushort4 d = pd4[q];
      rd[(i0 + 0) * RAS + o2] = bfu(d.x);
      rd[(i0 + 1) * RAS + o2] = bfu(d.y);
      rd[(i0 + 2) * RAS + o2] = bfu(d.z);
      rd[(i0 + 3) * RAS + o2] = bfu(d.w);
    }
  }
  __syncthreads();

  const int m16 = lane & 15;        // A-row within 16-tile / B-col within o-tile
  const int kq = (lane >> 4) * 8;   // k sub-offset
  const int nrow = w * 16 + m16;    // this lane's A row (n_loc) for loading
  const float* xrow = x + ((size_t)b * 8192 + n0 + nrow) * 64;

  floatx4 acc[4];
#pragma unroll
  for (int ot = 0; ot < 4; ++ot) acc[ot] = (floatx4){0.f, 0.f, 0.f, 0.f};

#pragma unroll
  for (int ks = 0; ks < 2; ++ks) {
    float4 xa = *(const float4*)(xrow + ks * 32 + kq);
    float4 xb = *(const float4*)(xrow + ks * 32 + kq + 4);
    short8 af;
    af[0] = f2bs(xa.x); af[1] = f2bs(xa.y); af[2] = f2bs(xa.z); af[3] = f2bs(xa.w);
    af[4] = f2bs(xb.x); af[5] = f2bs(xb.y); af[6] = f2bs(xb.z); af[7] = f2bs(xb.w);
#pragma unroll
    for (int ot = 0; ot < 4; ++ot) {
      short8 bf = *(const short8*)&Ktf[((ot * 2 + ks) * 64 + lane) * 8];
      acc[ot] = __builtin_amdgcn_mfma_f32_16x16x32_bf16(af, bf, acc[ot], 0, 0, 0);
    }
  }

  // epilogue: C/D layout col=lane&15 (o), row=(lane>>4)*4+reg (n)
  const int rbase = (lane >> 4) * 4;
#pragma unroll
  for (int ot = 0; ot < 4; ++ot) {
    int o_loc = ot * 16 + m16;
    float bo = bias[o_loc];
#pragma unroll
    for (int rg = 0; rg < 4; ++rg) {
      int n_loc = w * 16 + rbase + rg;
      int ul = n_loc >> 1, par = n_loc & 1;
      float wv = 0.f;
#pragma unroll
      for (int t = 0; t < 4; ++t) {
        int i = ul + 3 - t;
        float fl = par ? c_RL[2 * t + 1] : c_RL[2 * t];
        float fh = par ? c_RH[2 * t + 1] : c_RH[2 * t];
        wv += fl * ra[i * RAS + o_loc] + fh * rd[i * RAS + o_loc];
      }
      float v = acc[ot][rg] + wv + bo;
      float e = __expf(fminf(v, 15.f));
      float num = e * (e + 2.f);
      float mm = (v > 15.f) ? v : v * (num / (num + 2.f));
      // out is write-once, never re-read: nontemporal keeps L2/L3 for r1/d1.
      __builtin_nontemporal_store(mm, &out[((size_t)b * 8192 + n0 + n_loc) * 64 + o_loc]);
    }
  }
}

// ---------------- host ----------------
extern "C" void kernel_launch(void* const* d_in, const int* in_sizes, int n_in,
                              void* d_out, int out_size, void* d_ws, size_t ws_size,
                              hipStream_t stream) {
  const float* x    = (const float*)d_in[0];
  const float* w1   = (const float*)d_in[1];
  const float* w2   = (const float*)d_in[2];
  const float* dk   = (const float*)d_in[3];
  const float* bias = (const float*)d_in[4];
  float* out = (float*)d_out;

  const size_t R = 2048;

  float* wf = (float*)d_ws;
  float* d3f = wf; wf += R * 1030;
  float* a4t = wf; wf += R * 518;   // transposed: [p][i*32+b]
  float* d4t = wf; wf += R * 518;
  float* a4m = wf; wf += R * 518;   // mix outputs, row-major (b*64+o)
  float* d4m = wf; wf += R * 518;
  float* wt1 = wf; wf += (size_t)518 * 4096;  // transposed weights [p][i*64+o]
  float* wt2 = wf; wf += (size_t)518 * 4096;
  __hip_bfloat16* wb = (__hip_bfloat16*)wf;
  __hip_bfloat16* a1b = wb; wb += R * S1R;  // analysis a1, later recon1
  __hip_bfloat16* d1b = wb; wb += R * S1R;
  __hip_bfloat16* d2b = wb; wb += R * S2R;

  k_wT<<<dim3(64, 9, 2), 256, 0, stream>>>(w1, w2, wt1, wt2);
  k_dwt_first<<<dim3(65, 32), 256, 0, stream>>>(x, a1b, d1b);
  k_ana234<<<dim3(2048), 256, 0, stream>>>(a1b, d2b, d3f, a4t, d4t);
  k_mix_pc<<<dim3(518, 2), 256, 0, stream>>>(wt1, wt2, a4t, d4t, a4m, d4m);
  k_syn<<<dim3(2048), 256, 0, stream>>>(a4m, d4m, d3f, d2b, a1b);
  k_epilogue<<<dim3(128, 32), 256, 0, stream>>>(a1b, d1b, x, dk, bias, out);
}